// Round 1
// baseline (146.401 us; speedup 1.0000x reference)
//
#include <hip/hip_runtime.h>
#include <hip/hip_bf16.h>

// SupConLoss fused: logits = text @ image^T (bf16 MFMA), masked two-sided
// logsumexp with fixed shift, softplus-mean -> scalar.
// B = N = 8192, D = 256, NUM_CLASSES = 64, T = 1.

#define B_ROWS 8192
#define N_COLS 8192
#define DIM    256
#define CSPLIT 8           // column splits -> grid = (64, 8) = 512 blocks = 2/CU
#define WAVES  4           // 4 waves/block, each owns 32 rows -> 128 rows/block

typedef __attribute__((ext_vector_type(8)))  short bf16x8;   // 8 bf16 = 4 VGPR
typedef __attribute__((ext_vector_type(16))) float f32x16;   // MFMA 32x32 acc

#if __has_builtin(__builtin_amdgcn_exp2f)
#define EXP2F(x) __builtin_amdgcn_exp2f(x)
#else
#define EXP2F(x) exp2f(x)
#endif
#if __has_builtin(__builtin_amdgcn_logf)
#define LOG2F(x) __builtin_amdgcn_logf(x)
#else
#define LOG2F(x) log2f(x)
#endif

// f32 -> bf16 (RNE), 4 elements/thread
__global__ void cvt_bf16_kernel(const float* __restrict__ in,
                                unsigned short* __restrict__ out, int n4) {
    int i = blockIdx.x * blockDim.x + threadIdx.x;
    if (i >= n4) return;
    float4 v = reinterpret_cast<const float4*>(in)[i];
    union { float f; unsigned u; } c;
    ushort4 o;
    c.f = v.x; o.x = (unsigned short)((c.u + 0x7FFFu + ((c.u >> 16) & 1u)) >> 16);
    c.f = v.y; o.y = (unsigned short)((c.u + 0x7FFFu + ((c.u >> 16) & 1u)) >> 16);
    c.f = v.z; o.z = (unsigned short)((c.u + 0x7FFFu + ((c.u >> 16) & 1u)) >> 16);
    c.f = v.w; o.w = (unsigned short)((c.u + 0x7FFFu + ((c.u >> 16) & 1u)) >> 16);
    reinterpret_cast<ushort4*>(out)[i] = o;
}

// Fused GEMM + masked partial sum-of-exp.
// mfma_f32_32x32x16_bf16 layouts (HW-verified m74/m101 for C/D):
//   A: row = lane&31, k = 8*(lane>>5)+j   (8 contiguous k -> 16B load)
//   B: col = lane&31, k = 8*(lane>>5)+j   (image row-major -> 16B load)
//   C: col = lane&31, row = (r&3) + 8*(r>>2) + 4*(lane>>5)
__launch_bounds__(256, 2)
__global__ void fused_gemm_lse(const unsigned short* __restrict__ Abf,
                               const unsigned short* __restrict__ Bbf,
                               const int* __restrict__ tlab,
                               const int* __restrict__ itgt,
                               float* __restrict__ gsum_p,
                               float* __restrict__ gsum_n) {
    const int tid  = threadIdx.x;
    const int lane = tid & 63;
    const int wave = tid >> 6;
    const int half = lane >> 5;
    const int ln   = lane & 31;
    const int rb   = blockIdx.x * (32 * WAVES) + wave * 32;
    const int cb0  = blockIdx.y * (N_COLS / CSPLIT);

    // A fragments for all of K=256: 16 k-steps x 4 VGPR = 64 VGPR, loaded once.
    bf16x8 afrag[16];
    const bf16x8* arow =
        reinterpret_cast<const bf16x8*>(Abf + (size_t)(rb + ln) * DIM) + half;
#pragma unroll
    for (int ks = 0; ks < 16; ++ks) afrag[ks] = arow[ks * 2];

    // Row classes for the 16 accumulator slots (fixed for the whole block).
    int rowcls[16];
#pragma unroll
    for (int r = 0; r < 16; ++r) {
        int row = (r & 3) + 8 * (r >> 2) + 4 * half;
        rowcls[r] = tlab[rb + row];
    }

    float sump[16], sumn[16];
#pragma unroll
    for (int r = 0; r < 16; ++r) { sump[r] = 0.f; sumn[r] = 0.f; }

    const float L2E = 1.4426950408889634f;  // log2(e)
    const float C2  = 72.0f;                // fixed shift in log2 domain

    const int ntiles = (N_COLS / CSPLIT) / 32;
    for (int ct = 0; ct < ntiles; ++ct) {
        const int cb = cb0 + ct * 32;
        const int colcls = itgt[cb + ln];
        const bf16x8* brow =
            reinterpret_cast<const bf16x8*>(Bbf + (size_t)(cb + ln) * DIM) + half;

        f32x16 acc;
#pragma unroll
        for (int r = 0; r < 16; ++r) acc[r] = 0.f;
#pragma unroll
        for (int ks = 0; ks < 16; ++ks) {
            bf16x8 bfrag = brow[ks * 2];
            acc = __builtin_amdgcn_mfma_f32_32x32x16_bf16(afrag[ks], bfrag, acc,
                                                          0, 0, 0);
        }

        // Epilogue: route exp(+/-x - C) into pos/neg accumulators.
#pragma unroll
        for (int r = 0; r < 16; ++r) {
            const float x  = acc[r];
            const bool pos = (rowcls[r] == colcls);
            const float e  = EXP2F(__builtin_fmaf(x, pos ? -L2E : L2E, -C2));
            sump[r] += pos ? e : 0.f;
            sumn[r] += pos ? 0.f : e;
        }
    }

    // Reduce each row-sum across the 32 lanes of the half-wave, then atomics.
#pragma unroll
    for (int r = 0; r < 16; ++r) {
        float vp = sump[r], vn = sumn[r];
#pragma unroll
        for (int m = 1; m < 32; m <<= 1) {
            vp += __shfl_xor(vp, m, 64);
            vn += __shfl_xor(vn, m, 64);
        }
        if (ln == 0) {
            int row = rb + (r & 3) + 8 * (r >> 2) + 4 * half;
            atomicAdd(&gsum_p[row], vp);
            atomicAdd(&gsum_n[row], vn);
        }
    }
}

// lse_{p,n} = (log2(S) + C2) * ln2 ; loss = mean softplus(lse_p + lse_n)
__global__ void finalize_kernel(const float* __restrict__ gsum_p,
                                const float* __restrict__ gsum_n,
                                float* __restrict__ out) {
    __shared__ float red[1024];
    const float LN2 = 0.6931471805599453f;
    const float C2  = 72.0f;
    float acc = 0.f;
    for (int i = threadIdx.x; i < B_ROWS; i += 1024) {
        float zp = (LOG2F(gsum_p[i]) + C2) * LN2;
        float zn = (LOG2F(gsum_n[i]) + C2) * LN2;
        float z  = zp + zn;
        // stable softplus
        float sp = fmaxf(z, 0.f) + log1pf(expf(-fabsf(z)));
        acc += sp;
    }
    red[threadIdx.x] = acc;
    __syncthreads();
    for (int s = 512; s > 0; s >>= 1) {
        if ((int)threadIdx.x < s) red[threadIdx.x] += red[threadIdx.x + s];
        __syncthreads();
    }
    if (threadIdx.x == 0) out[0] = red[0] / (float)B_ROWS;
}

extern "C" void kernel_launch(void* const* d_in, const int* in_sizes, int n_in,
                              void* d_out, int out_size, void* d_ws, size_t ws_size,
                              hipStream_t stream) {
    const float* text = (const float*)d_in[0];   // [B, D] f32
    const float* img  = (const float*)d_in[1];   // [N, D] f32
    const int* tlab   = (const int*)d_in[2];     // [B]
    const int* itgt   = (const int*)d_in[3];     // [N]
    float* out        = (float*)d_out;           // scalar f32

    char* ws = (char*)d_ws;
    unsigned short* Abf = (unsigned short*)(ws);                        // 4 MB
    unsigned short* Bbf = (unsigned short*)(ws + (size_t)B_ROWS * DIM * 2); // 4 MB
    float* gsum_p = (float*)(ws + (size_t)(B_ROWS + N_COLS) * DIM * 2);
    float* gsum_n = gsum_p + B_ROWS;

    // f32 -> bf16 conversions
    {
        int n4 = (B_ROWS * DIM) / 4;
        cvt_bf16_kernel<<<(n4 + 255) / 256, 256, 0, stream>>>(text, Abf, n4);
        n4 = (N_COLS * DIM) / 4;
        cvt_bf16_kernel<<<(n4 + 255) / 256, 256, 0, stream>>>(img, Bbf, n4);
    }

    // zero the partial-sum accumulators (graph-capturable async memset)
    hipMemsetAsync(gsum_p, 0, (size_t)(B_ROWS * 2) * sizeof(float), stream);

    dim3 grid(B_ROWS / (32 * WAVES), CSPLIT);
    fused_gemm_lse<<<grid, 256, 0, stream>>>(Abf, Bbf, tlab, itgt, gsum_p, gsum_n);

    finalize_kernel<<<1, 1024, 0, stream>>>(gsum_p, gsum_n, out);
}